// Round 11
// baseline (430.702 us; speedup 1.0000x reference)
//
#include <hip/hip_runtime.h>

// 0.8*dice_loss(pred,target) + 0.2*soft_cldice_loss(pred,target)
// pred/target: (64,1,512,512) fp32 -> 1 fp32 scalar.
//
// soft_skeletonize = 10x: x = relu(x - (dil3(ero3(x)) - ero3(x)))
//   (inner relu dropped: dil3 includes self => dil3(e) >= e; verified R10+)
//   ero3 = 3x3 min-pool, x OOB -> +inf; dil3 = 3x3 max-pool, e OOB -> -inf
//
// R19: DOUBLE THE WAVES. R18's experiment resolved both open questions:
//   - K=5 cascade source kills the container (R16/R17) -> abandoned.
//   - (256,1) "spill fix" REGRESSED passA 146->203us: VGPR 168, occupancy
//     18.9->11.4%, VALUBusy 42->30%. Occupancy beats spill: R15's 44MB
//     priming spill costs ~7us of HBM; losing waves costs 57us.
// Diagnosis: latency-bound at 8 waves/CU (VALUBusy<=42%, HBM<=35% achv,
// zero conflicts; cascade = serial K-stage chain with 2 shuffles/stage).
// Fix: SROWS 32->16 -> 4096 waves = 16 waves/CU, exactly what the
// (256,2) VGPR=128 tier supports (R15-measured). Cost accepted: stepS
// work/row 5.6->7.1 (+28% VALU, headroom exists) and priming spill ~2x
// (~14us HBM, headroom exists). Single variable vs measured-good R15.
//
// R15 recap (measured 391us, absmax 0.0): K-stage register cascade;
// stage = 5 F8 (xc,xp,xn,eM,eC); stage i eats stage i-1's emitted row;
// priming fills stage j with 5 upstream rows. FETCH ~= unique bytes
// (L2/L3 absorb halo re-reads -> deeper fusion/smaller strips HBM-free).
//   passA: input -> g_A (iters 0-3) + dice sums on raw rows
//   passB: g_A -> g_B  (iters 4-7)
//   passC: g_B -> pairing reduction (iters 8-9, K=2)
//
// Harness rules learned: d_ws too small -> state in __device__ BSS;
// never pass __device__ symbols as host-side kernel args; launch_bounds
// trades VGPR vs occupancy ((256,4)=64cap spills catastrophically,
// (256,1)=fat-alloc kills TLP; (256,2)=128 is this kernel's sweet spot);
// global stores count toward vmcnt; K=5 cascade source kills the container.

#define H 512
#define W 512
#define NIMG 64
#define TOT 128
#define IMG_ELEMS (H * W)
#define SROWS 16
#define NSTRIPS (H / SROWS)          // 32 strips/unit
#define NDICE_SLOTS 64

__device__ float g_A[(size_t)TOT * IMG_ELEMS];    // 128 MiB
__device__ float g_B[(size_t)TOT * IMG_ELEMS];    // 128 MiB
__device__ float g_acc[NIMG * 4];                 // per-image pairing sums
__device__ float g_dice[NDICE_SLOTS * 16];        // spread dice accumulators

struct F8 { float4 a, b; };          // 8 consecutive columns per lane

__device__ __forceinline__ F8 f8fill(float v) {
  F8 r; r.a = make_float4(v, v, v, v); r.b = r.a; return r;
}
__device__ __forceinline__ F8 f8min(const F8& x, const F8& y) {
  F8 r;
  r.a.x = fminf(x.a.x, y.a.x); r.a.y = fminf(x.a.y, y.a.y);
  r.a.z = fminf(x.a.z, y.a.z); r.a.w = fminf(x.a.w, y.a.w);
  r.b.x = fminf(x.b.x, y.b.x); r.b.y = fminf(x.b.y, y.b.y);
  r.b.z = fminf(x.b.z, y.b.z); r.b.w = fminf(x.b.w, y.b.w);
  return r;
}
__device__ __forceinline__ F8 f8max(const F8& x, const F8& y) {
  F8 r;
  r.a.x = fmaxf(x.a.x, y.a.x); r.a.y = fmaxf(x.a.y, y.a.y);
  r.a.z = fmaxf(x.a.z, y.a.z); r.a.w = fmaxf(x.a.w, y.a.w);
  r.b.x = fmaxf(x.b.x, y.b.x); r.b.y = fmaxf(x.b.y, y.b.y);
  r.b.z = fmaxf(x.b.z, y.b.z); r.b.w = fmaxf(x.b.w, y.b.w);
  return r;
}
// horizontal 3-tap min; L/R image edges see +inf
__device__ __forceinline__ F8 ero8(const F8& v, int lane) {
  float L = __shfl_up(v.b.w, 1, 64);
  if (lane == 0) L = __builtin_inff();
  float R = __shfl_down(v.a.x, 1, 64);
  if (lane == 63) R = __builtin_inff();
  F8 e;
  e.a.x = fminf(L,     fminf(v.a.x, v.a.y));
  e.a.y = fminf(v.a.x, fminf(v.a.y, v.a.z));
  e.a.z = fminf(v.a.y, fminf(v.a.z, v.a.w));
  e.a.w = fminf(v.a.z, fminf(v.a.w, v.b.x));
  e.b.x = fminf(v.a.w, fminf(v.b.x, v.b.y));
  e.b.y = fminf(v.b.x, fminf(v.b.y, v.b.z));
  e.b.z = fminf(v.b.y, fminf(v.b.z, v.b.w));
  e.b.w = fminf(v.b.z, fminf(v.b.w, R));
  return e;
}
// horizontal 3-tap max; edges see -inf
__device__ __forceinline__ F8 dil8(const F8& v, int lane) {
  float L = __shfl_up(v.b.w, 1, 64);
  if (lane == 0) L = -__builtin_inff();
  float R = __shfl_down(v.a.x, 1, 64);
  if (lane == 63) R = -__builtin_inff();
  F8 d;
  d.a.x = fmaxf(L,     fmaxf(v.a.x, v.a.y));
  d.a.y = fmaxf(v.a.x, fmaxf(v.a.y, v.a.z));
  d.a.z = fmaxf(v.a.y, fmaxf(v.a.z, v.a.w));
  d.a.w = fmaxf(v.a.z, fmaxf(v.a.w, v.b.x));
  d.b.x = fmaxf(v.a.w, fmaxf(v.b.x, v.b.y));
  d.b.y = fmaxf(v.b.x, fmaxf(v.b.y, v.b.z));
  d.b.z = fmaxf(v.b.y, fmaxf(v.b.z, v.b.w));
  d.b.w = fmaxf(v.b.z, fmaxf(v.b.w, R));
  return d;
}
__device__ __forceinline__ F8 f8sub(const F8& x, const F8& y) {
  F8 r;
  r.a.x = x.a.x - y.a.x; r.a.y = x.a.y - y.a.y;
  r.a.z = x.a.z - y.a.z; r.a.w = x.a.w - y.a.w;
  r.b.x = x.b.x - y.b.x; r.b.y = x.b.y - y.b.y;
  r.b.z = x.b.z - y.b.z; r.b.w = x.b.w - y.b.w;
  return r;
}
__device__ __forceinline__ F8 f8relu_sub(const F8& x, const F8& y) {
  F8 r;
  r.a.x = fmaxf(x.a.x - y.a.x, 0.f); r.a.y = fmaxf(x.a.y - y.a.y, 0.f);
  r.a.z = fmaxf(x.a.z - y.a.z, 0.f); r.a.w = fmaxf(x.a.w - y.a.w, 0.f);
  r.b.x = fmaxf(x.b.x - y.b.x, 0.f); r.b.y = fmaxf(x.b.y - y.b.y, 0.f);
  r.b.z = fmaxf(x.b.z - y.b.z, 0.f); r.b.w = fmaxf(x.b.w - y.b.w, 0.f);
  return r;
}
__device__ __forceinline__ float f8dot(const F8& x, const float4& oa,
                                       const float4& ob) {
  return x.a.x * oa.x + x.a.y * oa.y + x.a.z * oa.z + x.a.w * oa.w
       + x.b.x * ob.x + x.b.y * ob.y + x.b.z * ob.z + x.b.w * ob.w;
}
__device__ __forceinline__ float f8sum(const F8& x) {
  return x.a.x + x.a.y + x.a.z + x.a.w + x.b.x + x.b.y + x.b.z + x.b.w;
}

// K fused skeletonize iterations, register cascade.
// Stage state (per stage i): xc=x[s], xp=x[s+1], xn=x[s+2], eM=e[s-1],
// eC=e[s]; one step consumes x[s+3] and emits y[s].
// MODE 0: store y (rows r0..r0+SROWS-1).
// MODE 1: store y; dice sums folded into stage-0 row loads:
//   isPred: a0 += sum(x*t), a1 += sum(x); else a2 += sum(x).
// MODE 2: no store; a0 += sum(y*other), a1 += sum(y).
template <int K, int MODE>
__device__ __forceinline__ void skelK(
    const float* __restrict__ src, float* __restrict__ dst,
    const float* __restrict__ oimg, bool isPred, int r0, int lane,
    float out3[3]) {
  const float PINF = __builtin_inff();
  float a0 = 0.f, a1 = 0.f, a2 = 0.f;

  F8 xc[K], xp[K], xn[K], eM[K], eC[K];
  int sr[K];                                   // wave-uniform emission rows

  int in_row = r0 - 2 * (K - 1) - 2;           // first input row consumed

  auto loadrow = [&](int r) -> F8 {
    F8 v;
    if (r >= 0 && r < H) {
      const float4* rp = (const float4*)(src + (size_t)r * W);
      v.a = rp[lane * 2];
      v.b = rp[lane * 2 + 1];
      if (MODE == 1 && r >= r0 && r < r0 + SROWS) {  // each owned row once
        if (isPred) {
          const float4* tp = (const float4*)(oimg + (size_t)r * W);
          float4 ta = tp[lane * 2], tb = tp[lane * 2 + 1];
          a0 += f8dot(v, ta, tb);
          a1 += f8sum(v);
        } else {
          a2 += f8sum(v);
        }
      }
    } else {
      v = f8fill(PINF);                        // image OOB rows: +inf
    }
    return v;
  };

  auto erow = [&](const F8& x0, const F8& x1, const F8& x2, int r) -> F8 {
    F8 e = ero8(f8min(f8min(x0, x1), x2), lane);
    if (r < 0 || r >= H) e = f8fill(-PINF);    // e OOB: -inf (dil pad)
    return e;
  };

  auto stepS = [&](int i, F8 in) -> F8 {       // i static under full unroll
    F8 eP = erow(xc[i], xp[i], xn[i], sr[i] + 1);
    F8 d  = dil8(f8max(f8max(eM[i], eC[i]), eP), lane);
    F8 y  = f8relu_sub(xc[i], f8sub(d, eC[i]));
    if (sr[i] < 0 || sr[i] >= H) y = f8fill(PINF);  // next stage sees +inf
    xc[i] = xp[i]; xp[i] = xn[i]; xn[i] = in;
    eM[i] = eC[i]; eC[i] = eP; sr[i]++;
    return y;
  };

  // step stages 0..m with one fresh top input; m is compile-time at every
  // call site (prime j uses m=j-1, main uses m=K-1) -> static indexing.
  auto cascade = [&](int m, F8 top) -> F8 {
    F8 v = top;
    #pragma unroll
    for (int i = 0; i < K; ++i)
      if (i <= m) v = stepS(i, v);
    return v;
  };

  // ---- prime stages 0..K-1 (stage j eats 5 rows from upstream) ----
  #pragma unroll
  for (int j = 0; j < K; ++j) {
    const int fj = r0 - 2 * (K - 1 - j);       // stage j first emission row
    F8 v[5];
    #pragma unroll
    for (int t = 0; t < 5; ++t)
      v[t] = cascade(j - 1, loadrow(in_row++));
    eM[j] = erow(v[0], v[1], v[2], fj - 1);
    eC[j] = erow(v[1], v[2], v[3], fj);
    xc[j] = v[2]; xp[j] = v[3]; xn[j] = v[4];
    sr[j] = fj;
  }

  // ---- main: SROWS full-cascade steps; last stage emits rows r0+t ----
  #pragma unroll 1
  for (int t = 0; t < SROWS; ++t) {
    float4 oa, ob;
    if (MODE == 2) {                           // issue operand load early;
      const float4* op =                       // consumed after ~K*150cy
          (const float4*)(oimg + (size_t)(r0 + t) * W);
      oa = op[lane * 2];
      ob = op[lane * 2 + 1];
    }
    F8 y = cascade(K - 1, loadrow(in_row++));
    if (MODE == 2) {
      a0 += f8dot(y, oa, ob);
      a1 += f8sum(y);
    } else {
      float4* dp = (float4*)(dst + (size_t)(r0 + t) * W);
      dp[lane * 2]     = y.a;
      dp[lane * 2 + 1] = y.b;
    }
  }

  if (MODE != 0) {
    #pragma unroll
    for (int o = 32; o; o >>= 1) {
      a0 += __shfl_down(a0, o, 64);
      a1 += __shfl_down(a1, o, 64);
      if (MODE == 1) a2 += __shfl_down(a2, o, 64);
    }
    out3[0] = a0; out3[1] = a1; out3[2] = a2;
  }
}

// Pass A: ext inputs -> g_A (iters 0-3) + dice sums.
__global__ __launch_bounds__(256, 2) void passA(
    const float* __restrict__ pred, const float* __restrict__ target) {
  const int wid  = blockIdx.x * 4 + (threadIdx.x >> 6);
  const int lane = threadIdx.x & 63;
  const int u    = wid / NSTRIPS;              // 0..127
  const int r0   = (wid % NSTRIPS) * SROWS;
  const bool isPred = (u < NIMG);
  const float* src = isPred ? pred + (size_t)u * IMG_ELEMS
                            : target + (size_t)(u - NIMG) * IMG_ELEMS;
  const float* o = isPred ? target + (size_t)u * IMG_ELEMS : nullptr;
  float* dst = (float*)g_A + (size_t)u * IMG_ELEMS;

  float out3[3] = {0.f, 0.f, 0.f};
  skelK<4, 1>(src, dst, o, isPred, r0, lane, out3);

  __shared__ float red[4][3];
  const int wave = threadIdx.x >> 6;
  if (lane == 0) {
    red[wave][0] = out3[0]; red[wave][1] = out3[1]; red[wave][2] = out3[2];
  }
  __syncthreads();
  if (threadIdx.x < 3) {
    float sv = red[0][threadIdx.x] + red[1][threadIdx.x] +
               red[2][threadIdx.x] + red[3][threadIdx.x];
    atomicAdd(&g_dice[(blockIdx.x & (NDICE_SLOTS - 1)) * 16 + threadIdx.x], sv);
  }
}

// Pass B: g_A -> g_B (iters 4-7).
__global__ __launch_bounds__(256, 2) void passB() {
  const int wid  = blockIdx.x * 4 + (threadIdx.x >> 6);
  const int lane = threadIdx.x & 63;
  const int u    = wid / NSTRIPS;
  const int r0   = (wid % NSTRIPS) * SROWS;
  skelK<4, 0>((const float*)g_A + (size_t)u * IMG_ELEMS,
              (float*)g_B + (size_t)u * IMG_ELEMS,
              nullptr, false, r0, lane, nullptr);
}

// Pass C: g_B -> iters 8,9 fused with pairing reduction.
__global__ __launch_bounds__(256) void passC(
    const float* __restrict__ pred, const float* __restrict__ target) {
  const int wid  = blockIdx.x * 4 + (threadIdx.x >> 6);
  const int lane = threadIdx.x & 63;
  const int u    = wid / NSTRIPS;
  const int r0   = (wid % NSTRIPS) * SROWS;
  const bool isPred = (u < NIMG);
  const int img = isPred ? u : u - NIMG;
  const int accBase = isPred ? 0 : 2;
  const float* src = (const float*)g_B + (size_t)u * IMG_ELEMS;
  const float* o = isPred ? target + (size_t)img * IMG_ELEMS
                          : pred + (size_t)img * IMG_ELEMS;

  float out3[3] = {0.f, 0.f, 0.f};
  skelK<2, 2>(src, nullptr, o, isPred, r0, lane, out3);

  __shared__ float red[4][2];
  const int wave = threadIdx.x >> 6;
  if (lane == 0) { red[wave][0] = out3[0]; red[wave][1] = out3[1]; }
  __syncthreads();
  if (threadIdx.x < 2) {
    float sv = red[0][threadIdx.x] + red[1][threadIdx.x] +
               red[2][threadIdx.x] + red[3][threadIdx.x];
    atomicAdd(&g_acc[img * 4 + accBase + threadIdx.x], sv);
  }
}

__global__ void zero_acc() {
  for (int i = threadIdx.x; i < NIMG * 4; i += 256) g_acc[i] = 0.0f;
  for (int i = threadIdx.x; i < NDICE_SLOTS * 16; i += 256) g_dice[i] = 0.0f;
}

__global__ void final_kernel(float* __restrict__ out) {
  const int lane = threadIdx.x;  // 64 threads = 64 images / 64 dice slots
  float s1 = g_acc[lane * 4 + 0], s2 = g_acc[lane * 4 + 1];
  float s3 = g_acc[lane * 4 + 2], s4 = g_acc[lane * 4 + 3];
  float iflat = (s1 + 1.0f) / (s2 + 1.0f);
  float tflat = (s3 + 1.0f) / (s4 + 1.0f);
  float prod = iflat * tflat;
  float ssum = iflat + tflat;
  float d0 = g_dice[lane * 16 + 0];
  float d1 = g_dice[lane * 16 + 1];
  float d2 = g_dice[lane * 16 + 2];
  #pragma unroll
  for (int o = 32; o; o >>= 1) {
    prod += __shfl_down(prod, o, 64);
    ssum += __shfl_down(ssum, o, 64);
    d0   += __shfl_down(d0, o, 64);
    d1   += __shfl_down(d1, o, 64);
    d2   += __shfl_down(d2, o, 64);
  }
  if (lane == 0) {
    float cldice = 1.0f - 2.0f * prod / ssum;
    float dice = 1.0f - (2.0f * d0 + 1e-6f) / (d1 + d2 + 1e-6f);
    out[0] = 0.8f * dice + 0.2f * cldice;
  }
}

extern "C" void kernel_launch(void* const* d_in, const int* in_sizes, int n_in,
                              void* d_out, int out_size, void* d_ws, size_t ws_size,
                              hipStream_t stream) {
  const float* pred   = (const float*)d_in[0];
  const float* target = (const float*)d_in[1];
  float* out = (float*)d_out;
  (void)d_ws; (void)ws_size;

  const int nblocks = TOT * NSTRIPS / 4;       // 1024 blocks of 4 waves

  zero_acc<<<1, 256, 0, stream>>>();
  passA<<<nblocks, 256, 0, stream>>>(pred, target);  // iters 0-3 + dice
  passB<<<nblocks, 256, 0, stream>>>();              // iters 4-7
  passC<<<nblocks, 256, 0, stream>>>(pred, target);  // iters 8-9 + pairing
  final_kernel<<<1, 64, 0, stream>>>(out);
}

// Round 13
// 377.094 us; speedup vs baseline: 1.1422x; 1.1422x over previous
//
#include <hip/hip_runtime.h>

// 0.8*dice_loss(pred,target) + 0.2*soft_cldice_loss(pred,target)
// pred/target: (64,1,512,512) fp32 -> 1 fp32 scalar.
//
// soft_skeletonize = 10x: x = relu(x - (dil3(ero3(x)) - ero3(x)))
//   (inner relu dropped: dil3 includes self => dil3(e) >= e; verified R10+)
//   ero3 = 3x3 min-pool, x OOB -> +inf; dil3 = 3x3 max-pool, e OOB -> -inf
//
// R21: UNROLL 2 (R20's theory, half the dose). R20 (unroll 4) hit the
// "container failed twice" signature — third source-correlated failure,
// all on heavy-code-expansion variants (K=5: R16/R17; unroll4: R20),
// while moderate kernels (R15/R18/R19) run fine. Mechanism: compiler
// time / regalloc thrash on giant unrolled bodies blows the container
// budget. The underlying perf theory stands: R15 spends ~61us/pass on
// VALU issue (~2x useful ops) because '#pragma unroll 1' forces ~40
// state-rotation movs per stepS and serializes consecutive rows' shuffle
// chains. unroll 2 gets the register-renaming + cross-row ILP at half
// R20's expansion (8 stepS bodies in main loop ~= priming section size,
// which always compiled fine). Single variable vs measured-good R15.
//
// R15 recap (measured 391us, absmax 0.0): K-stage register cascade;
// stage = 5 F8 (xc,xp,xn,eM,eC); stage i eats stage i-1's emitted row;
// priming fills stage j with 5 upstream rows. FETCH ~= unique bytes
// (L2/L3 absorb halo re-reads).
//   passA: input -> g_A (iters 0-3) + dice sums on raw rows
//   passB: g_A -> g_B  (iters 4-7)
//   passC: g_B -> pairing reduction (iters 8-9, K=2)
//
// Harness rules learned: d_ws too small -> state in __device__ BSS;
// never pass __device__ symbols as host-side kernel args; launch_bounds
// trades VGPR vs occupancy ((256,4)=64cap spills catastrophically,
// (256,1)=fat-alloc kills TLP, (256,2)=128 sweet spot); occupancy is NOT
// grid-limited at this VGPR tier (R19); global stores count toward vmcnt;
// heavy code expansion (K=5, unroll4) kills the container (R16/R17/R20).

#define H 512
#define W 512
#define NIMG 64
#define TOT 128
#define IMG_ELEMS (H * W)
#define SROWS 32
#define NSTRIPS (H / SROWS)          // 16 strips/unit
#define NDICE_SLOTS 64

__device__ float g_A[(size_t)TOT * IMG_ELEMS];    // 128 MiB
__device__ float g_B[(size_t)TOT * IMG_ELEMS];    // 128 MiB
__device__ float g_acc[NIMG * 4];                 // per-image pairing sums
__device__ float g_dice[NDICE_SLOTS * 16];        // spread dice accumulators

struct F8 { float4 a, b; };          // 8 consecutive columns per lane

__device__ __forceinline__ F8 f8fill(float v) {
  F8 r; r.a = make_float4(v, v, v, v); r.b = r.a; return r;
}
__device__ __forceinline__ F8 f8min(const F8& x, const F8& y) {
  F8 r;
  r.a.x = fminf(x.a.x, y.a.x); r.a.y = fminf(x.a.y, y.a.y);
  r.a.z = fminf(x.a.z, y.a.z); r.a.w = fminf(x.a.w, y.a.w);
  r.b.x = fminf(x.b.x, y.b.x); r.b.y = fminf(x.b.y, y.b.y);
  r.b.z = fminf(x.b.z, y.b.z); r.b.w = fminf(x.b.w, y.b.w);
  return r;
}
__device__ __forceinline__ F8 f8max(const F8& x, const F8& y) {
  F8 r;
  r.a.x = fmaxf(x.a.x, y.a.x); r.a.y = fmaxf(x.a.y, y.a.y);
  r.a.z = fmaxf(x.a.z, y.a.z); r.a.w = fmaxf(x.a.w, y.a.w);
  r.b.x = fmaxf(x.b.x, y.b.x); r.b.y = fmaxf(x.b.y, y.b.y);
  r.b.z = fmaxf(x.b.z, y.b.z); r.b.w = fmaxf(x.b.w, y.b.w);
  return r;
}
// horizontal 3-tap min; L/R image edges see +inf
__device__ __forceinline__ F8 ero8(const F8& v, int lane) {
  float L = __shfl_up(v.b.w, 1, 64);
  if (lane == 0) L = __builtin_inff();
  float R = __shfl_down(v.a.x, 1, 64);
  if (lane == 63) R = __builtin_inff();
  F8 e;
  e.a.x = fminf(L,     fminf(v.a.x, v.a.y));
  e.a.y = fminf(v.a.x, fminf(v.a.y, v.a.z));
  e.a.z = fminf(v.a.y, fminf(v.a.z, v.a.w));
  e.a.w = fminf(v.a.z, fminf(v.a.w, v.b.x));
  e.b.x = fminf(v.a.w, fminf(v.b.x, v.b.y));
  e.b.y = fminf(v.b.x, fminf(v.b.y, v.b.z));
  e.b.z = fminf(v.b.y, fminf(v.b.z, v.b.w));
  e.b.w = fminf(v.b.z, fminf(v.b.w, R));
  return e;
}
// horizontal 3-tap max; edges see -inf
__device__ __forceinline__ F8 dil8(const F8& v, int lane) {
  float L = __shfl_up(v.b.w, 1, 64);
  if (lane == 0) L = -__builtin_inff();
  float R = __shfl_down(v.a.x, 1, 64);
  if (lane == 63) R = -__builtin_inff();
  F8 d;
  d.a.x = fmaxf(L,     fmaxf(v.a.x, v.a.y));
  d.a.y = fmaxf(v.a.x, fmaxf(v.a.y, v.a.z));
  d.a.z = fmaxf(v.a.y, fmaxf(v.a.z, v.a.w));
  d.a.w = fmaxf(v.a.z, fmaxf(v.a.w, v.b.x));
  d.b.x = fmaxf(v.a.w, fmaxf(v.b.x, v.b.y));
  d.b.y = fmaxf(v.b.x, fmaxf(v.b.y, v.b.z));
  d.b.z = fmaxf(v.b.y, fmaxf(v.b.z, v.b.w));
  d.b.w = fmaxf(v.b.z, fmaxf(v.b.w, R));
  return d;
}
__device__ __forceinline__ F8 f8sub(const F8& x, const F8& y) {
  F8 r;
  r.a.x = x.a.x - y.a.x; r.a.y = x.a.y - y.a.y;
  r.a.z = x.a.z - y.a.z; r.a.w = x.a.w - y.a.w;
  r.b.x = x.b.x - y.b.x; r.b.y = x.b.y - y.b.y;
  r.b.z = x.b.z - y.b.z; r.b.w = x.b.w - y.b.w;
  return r;
}
__device__ __forceinline__ F8 f8relu_sub(const F8& x, const F8& y) {
  F8 r;
  r.a.x = fmaxf(x.a.x - y.a.x, 0.f); r.a.y = fmaxf(x.a.y - y.a.y, 0.f);
  r.a.z = fmaxf(x.a.z - y.a.z, 0.f); r.a.w = fmaxf(x.a.w - y.a.w, 0.f);
  r.b.x = fmaxf(x.b.x - y.b.x, 0.f); r.b.y = fmaxf(x.b.y - y.b.y, 0.f);
  r.b.z = fmaxf(x.b.z - y.b.z, 0.f); r.b.w = fmaxf(x.b.w - y.b.w, 0.f);
  return r;
}
__device__ __forceinline__ float f8dot(const F8& x, const float4& oa,
                                       const float4& ob) {
  return x.a.x * oa.x + x.a.y * oa.y + x.a.z * oa.z + x.a.w * oa.w
       + x.b.x * ob.x + x.b.y * ob.y + x.b.z * ob.z + x.b.w * ob.w;
}
__device__ __forceinline__ float f8sum(const F8& x) {
  return x.a.x + x.a.y + x.a.z + x.a.w + x.b.x + x.b.y + x.b.z + x.b.w;
}

// K fused skeletonize iterations, register cascade.
// Stage state (per stage i): xc=x[s], xp=x[s+1], xn=x[s+2], eM=e[s-1],
// eC=e[s]; one step consumes x[s+3] and emits y[s].
// MODE 0: store y (rows r0..r0+SROWS-1).
// MODE 1: store y; dice sums folded into stage-0 row loads:
//   isPred: a0 += sum(x*t), a1 += sum(x); else a2 += sum(x).
// MODE 2: no store; a0 += sum(y*other), a1 += sum(y).
template <int K, int MODE>
__device__ __forceinline__ void skelK(
    const float* __restrict__ src, float* __restrict__ dst,
    const float* __restrict__ oimg, bool isPred, int r0, int lane,
    float out3[3]) {
  const float PINF = __builtin_inff();
  float a0 = 0.f, a1 = 0.f, a2 = 0.f;

  F8 xc[K], xp[K], xn[K], eM[K], eC[K];
  int sr[K];                                   // wave-uniform emission rows

  int in_row = r0 - 2 * (K - 1) - 2;           // first input row consumed

  auto loadrow = [&](int r) -> F8 {
    F8 v;
    if (r >= 0 && r < H) {
      const float4* rp = (const float4*)(src + (size_t)r * W);
      v.a = rp[lane * 2];
      v.b = rp[lane * 2 + 1];
      if (MODE == 1 && r >= r0 && r < r0 + SROWS) {  // each owned row once
        if (isPred) {
          const float4* tp = (const float4*)(oimg + (size_t)r * W);
          float4 ta = tp[lane * 2], tb = tp[lane * 2 + 1];
          a0 += f8dot(v, ta, tb);
          a1 += f8sum(v);
        } else {
          a2 += f8sum(v);
        }
      }
    } else {
      v = f8fill(PINF);                        // image OOB rows: +inf
    }
    return v;
  };

  auto erow = [&](const F8& x0, const F8& x1, const F8& x2, int r) -> F8 {
    F8 e = ero8(f8min(f8min(x0, x1), x2), lane);
    if (r < 0 || r >= H) e = f8fill(-PINF);    // e OOB: -inf (dil pad)
    return e;
  };

  auto stepS = [&](int i, F8 in) -> F8 {       // i static under full unroll
    F8 eP = erow(xc[i], xp[i], xn[i], sr[i] + 1);
    F8 d  = dil8(f8max(f8max(eM[i], eC[i]), eP), lane);
    F8 y  = f8relu_sub(xc[i], f8sub(d, eC[i]));
    if (sr[i] < 0 || sr[i] >= H) y = f8fill(PINF);  // next stage sees +inf
    xc[i] = xp[i]; xp[i] = xn[i]; xn[i] = in;
    eM[i] = eC[i]; eC[i] = eP; sr[i]++;
    return y;
  };

  // step stages 0..m with one fresh top input; m is compile-time at every
  // call site (prime j uses m=j-1, main uses m=K-1) -> static indexing.
  auto cascade = [&](int m, F8 top) -> F8 {
    F8 v = top;
    #pragma unroll
    for (int i = 0; i < K; ++i)
      if (i <= m) v = stepS(i, v);
    return v;
  };

  // ---- prime stages 0..K-1 (stage j eats 5 rows from upstream) ----
  #pragma unroll
  for (int j = 0; j < K; ++j) {
    const int fj = r0 - 2 * (K - 1 - j);       // stage j first emission row
    F8 v[5];
    #pragma unroll
    for (int t = 0; t < 5; ++t)
      v[t] = cascade(j - 1, loadrow(in_row++));
    eM[j] = erow(v[0], v[1], v[2], fj - 1);
    eC[j] = erow(v[1], v[2], v[3], fj);
    xc[j] = v[2]; xp[j] = v[3]; xn[j] = v[4];
    sr[j] = fj;
  }

  // ---- main: SROWS full-cascade steps; last stage emits rows r0+t ----
  // unroll 2: state rotations become register renames and consecutive
  // rows' shuffle chains overlap, at half R20's (container-killing) code
  // expansion.
  #pragma unroll 2
  for (int t = 0; t < SROWS; ++t) {
    float4 oa, ob;
    if (MODE == 2) {                           // issue operand load early;
      const float4* op =                       // consumed after ~K*150cy
          (const float4*)(oimg + (size_t)(r0 + t) * W);
      oa = op[lane * 2];
      ob = op[lane * 2 + 1];
    }
    F8 y = cascade(K - 1, loadrow(in_row++));
    if (MODE == 2) {
      a0 += f8dot(y, oa, ob);
      a1 += f8sum(y);
    } else {
      float4* dp = (float4*)(dst + (size_t)(r0 + t) * W);
      dp[lane * 2]     = y.a;
      dp[lane * 2 + 1] = y.b;
    }
  }

  if (MODE != 0) {
    #pragma unroll
    for (int o = 32; o; o >>= 1) {
      a0 += __shfl_down(a0, o, 64);
      a1 += __shfl_down(a1, o, 64);
      if (MODE == 1) a2 += __shfl_down(a2, o, 64);
    }
    out3[0] = a0; out3[1] = a1; out3[2] = a2;
  }
}

// Pass A: ext inputs -> g_A (iters 0-3) + dice sums.
__global__ __launch_bounds__(256, 2) void passA(
    const float* __restrict__ pred, const float* __restrict__ target) {
  const int wid  = blockIdx.x * 4 + (threadIdx.x >> 6);
  const int lane = threadIdx.x & 63;
  const int u    = wid / NSTRIPS;              // 0..127
  const int r0   = (wid % NSTRIPS) * SROWS;
  const bool isPred = (u < NIMG);
  const float* src = isPred ? pred + (size_t)u * IMG_ELEMS
                            : target + (size_t)(u - NIMG) * IMG_ELEMS;
  const float* o = isPred ? target + (size_t)u * IMG_ELEMS : nullptr;
  float* dst = (float*)g_A + (size_t)u * IMG_ELEMS;

  float out3[3] = {0.f, 0.f, 0.f};
  skelK<4, 1>(src, dst, o, isPred, r0, lane, out3);

  __shared__ float red[4][3];
  const int wave = threadIdx.x >> 6;
  if (lane == 0) {
    red[wave][0] = out3[0]; red[wave][1] = out3[1]; red[wave][2] = out3[2];
  }
  __syncthreads();
  if (threadIdx.x < 3) {
    float sv = red[0][threadIdx.x] + red[1][threadIdx.x] +
               red[2][threadIdx.x] + red[3][threadIdx.x];
    atomicAdd(&g_dice[(blockIdx.x & (NDICE_SLOTS - 1)) * 16 + threadIdx.x], sv);
  }
}

// Pass B: g_A -> g_B (iters 4-7).
__global__ __launch_bounds__(256, 2) void passB() {
  const int wid  = blockIdx.x * 4 + (threadIdx.x >> 6);
  const int lane = threadIdx.x & 63;
  const int u    = wid / NSTRIPS;
  const int r0   = (wid % NSTRIPS) * SROWS;
  skelK<4, 0>((const float*)g_A + (size_t)u * IMG_ELEMS,
              (float*)g_B + (size_t)u * IMG_ELEMS,
              nullptr, false, r0, lane, nullptr);
}

// Pass C: g_B -> iters 8,9 fused with pairing reduction.
__global__ __launch_bounds__(256) void passC(
    const float* __restrict__ pred, const float* __restrict__ target) {
  const int wid  = blockIdx.x * 4 + (threadIdx.x >> 6);
  const int lane = threadIdx.x & 63;
  const int u    = wid / NSTRIPS;
  const int r0   = (wid % NSTRIPS) * SROWS;
  const bool isPred = (u < NIMG);
  const int img = isPred ? u : u - NIMG;
  const int accBase = isPred ? 0 : 2;
  const float* src = (const float*)g_B + (size_t)u * IMG_ELEMS;
  const float* o = isPred ? target + (size_t)img * IMG_ELEMS
                          : pred + (size_t)img * IMG_ELEMS;

  float out3[3] = {0.f, 0.f, 0.f};
  skelK<2, 2>(src, nullptr, o, isPred, r0, lane, out3);

  __shared__ float red[4][2];
  const int wave = threadIdx.x >> 6;
  if (lane == 0) { red[wave][0] = out3[0]; red[wave][1] = out3[1]; }
  __syncthreads();
  if (threadIdx.x < 2) {
    float sv = red[0][threadIdx.x] + red[1][threadIdx.x] +
               red[2][threadIdx.x] + red[3][threadIdx.x];
    atomicAdd(&g_acc[img * 4 + accBase + threadIdx.x], sv);
  }
}

__global__ void zero_acc() {
  for (int i = threadIdx.x; i < NIMG * 4; i += 256) g_acc[i] = 0.0f;
  for (int i = threadIdx.x; i < NDICE_SLOTS * 16; i += 256) g_dice[i] = 0.0f;
}

__global__ void final_kernel(float* __restrict__ out) {
  const int lane = threadIdx.x;  // 64 threads = 64 images / 64 dice slots
  float s1 = g_acc[lane * 4 + 0], s2 = g_acc[lane * 4 + 1];
  float s3 = g_acc[lane * 4 + 2], s4 = g_acc[lane * 4 + 3];
  float iflat = (s1 + 1.0f) / (s2 + 1.0f);
  float tflat = (s3 + 1.0f) / (s4 + 1.0f);
  float prod = iflat * tflat;
  float ssum = iflat + tflat;
  float d0 = g_dice[lane * 16 + 0];
  float d1 = g_dice[lane * 16 + 1];
  float d2 = g_dice[lane * 16 + 2];
  #pragma unroll
  for (int o = 32; o; o >>= 1) {
    prod += __shfl_down(prod, o, 64);
    ssum += __shfl_down(ssum, o, 64);
    d0   += __shfl_down(d0, o, 64);
    d1   += __shfl_down(d1, o, 64);
    d2   += __shfl_down(d2, o, 64);
  }
  if (lane == 0) {
    float cldice = 1.0f - 2.0f * prod / ssum;
    float dice = 1.0f - (2.0f * d0 + 1e-6f) / (d1 + d2 + 1e-6f);
    out[0] = 0.8f * dice + 0.2f * cldice;
  }
}

extern "C" void kernel_launch(void* const* d_in, const int* in_sizes, int n_in,
                              void* d_out, int out_size, void* d_ws, size_t ws_size,
                              hipStream_t stream) {
  const float* pred   = (const float*)d_in[0];
  const float* target = (const float*)d_in[1];
  float* out = (float*)d_out;
  (void)d_ws; (void)ws_size;

  const int nblocks = TOT * NSTRIPS / 4;       // 512 blocks of 4 waves

  zero_acc<<<1, 256, 0, stream>>>();
  passA<<<nblocks, 256, 0, stream>>>(pred, target);  // iters 0-3 + dice
  passB<<<nblocks, 256, 0, stream>>>();              // iters 4-7
  passC<<<nblocks, 256, 0, stream>>>(pred, target);  // iters 8-9 + pairing
  final_kernel<<<1, 64, 0, stream>>>(out);
}